// Round 12
// baseline (480.716 us; speedup 1.0000x reference)
//
#include <hip/hip_runtime.h>
#include <hip/hip_bf16.h>
#include <stdint.h>

// ObjectDetectionLoss (SSD MultiBox) — MI355X / gfx950
// B=64, N=16800, C=21. Output: 3 fp32 scalars.
//
// Round-12 = round-11 resubmit (r11 died to GPUAcquisitionTimeout; the fused
// kernel has never run). Lessons: r2 = no hot global atomics (a few K total
// fine); r3 = no clustered LDS-atomic hist; r6 = no tid==0 serial bin-walks;
// r7 = no block-barrier staging convoy; r9/r10 post-mortem: x[gl]
// runtime-indexed a 21-register array -> scratch allocation (~180MB hidden
// traffic) — keep the gl-indexed access in LDS (rule #20).
//
// Single fused kernel k_all (4224 x 256):
//   Phase A (all blocks): wave-cooperative logit staging (6 coalesced float4
//     per lane -> wave-private LDS, NO block barrier), per-anchor SL1 + CE
//     (x[gl] read from LDS), ce_neg store, per-block stats -> partial.
//   Arrival: per-batch counter (66 blocks); LAST block of each batch runs the
//     select phase for that batch, re-reading ce_neg from L2/L3 (no big LDS):
//     ballot-hist 256 bins -> wave-parallel suffix scan -> 3 refine passes
//     (mantissa bits, wave-parallel picks) -> exact k-th bits T ->
//     sum(v>T) + r*T (tie-exact fp64) -> publish flb/fll/fpn.
//   Last select block reduces over B -> out (r10-validated fence pattern).
// + hipMemsetAsync(512B) for the counters.

#define NB 64
#define NN 16800
#define NC 21
#define BPB 66                    // blocks per batch (66*256 = 16896 >= 16800)
#define NBLK (NB * BPB)           // 4224
#define FP32_EPS_F 1.1920928955078125e-07f

// ---------------- workspace layout (bytes) — total 4,370,176 (< proven 4.44MB)
#define OFF_PARTIAL 0u            // float4 [4224] = 67584
#define OFF_FLB     67584u        // double [64] -> 68096
#define OFF_FLL     68096u        // double [64] -> 68608
#define OFF_FPN     68608u        // int    [64] -> 68864
#define OFF_BCNT    68864u        // int    [64] -> 69120   (memset 0)
#define OFF_DONE2   69120u        // int    [1]  -> 69376 (pad; memset 0)
#define OFF_CENEG   69376u        // float  [NB*NN] = 4300800 -> 4370176

// ===================== fused kernel =====================
__global__ __launch_bounds__(256) void k_all(
    const float* __restrict__ p_bboxs, const float* __restrict__ g_bboxs,
    const float* __restrict__ p_labels, const int* __restrict__ g_labels,
    const float* __restrict__ ancs,
    float* __restrict__ ce_neg, float4* __restrict__ partial,
    double* __restrict__ flb, double* __restrict__ fll, int* __restrict__ fpn,
    int* __restrict__ bcnt, int* __restrict__ done2, float* __restrict__ out)
{
    __shared__ float lds_rows[4][1344];        // 21504 B: per-wave 64 rows x 21
    __shared__ float st[4];                    // pos, sl1, ce
    __shared__ int s_old;
    __shared__ uint32_t hist[256];
    __shared__ uint32_t h2[256];
    __shared__ float s_stats[4];
    __shared__ uint32_t s_cur;
    __shared__ int s_need;
    __shared__ double dpart[4];
    __shared__ int s_last;

    const int tid = threadIdx.x, lane = tid & 63, w = tid >> 6;
    const int b = blockIdx.x / BPB;
    const int j = blockIdx.x - b * BPB;
    const int nbase = j * 256;
    const int nact = (NN - nbase) < 256 ? (NN - nbase) : 256;   // 256 or 160
    int nw = nact - w * 64;                    // valid lanes in this wave
    nw = nw < 0 ? 0 : (nw > 64 ? 64 : nw);
    const bool valid = lane < nw;

    if (tid < 4) st[tid] = 0.f;
    __syncthreads();                           // st init before pos atomics

    // ---- per-thread bbox/label loads (coalesced float4/dword), issued early ----
    float4 p, g, a; int gl = 0;
    const int idx = b * NN + nbase + tid;
    if (valid) {
        p = ((const float4*)p_bboxs)[idx];
        g = ((const float4*)g_bboxs)[idx];
        a = ((const float4*)ancs)[nbase + tid];
        gl = g_labels[idx];
    }

    // ---- wave-cooperative logit staging: 64 rows = 5376B = 336 float4,
    //      perfectly coalesced+aligned; wave-private LDS; NO block barrier ----
    {
        const int wanchor = b * NN + nbase + w * 64;   // == 0 mod 4 -> 16B aligned
        const float4* src4 = (const float4*)p_labels + ((size_t)wanchor * NC) / 4;
        float4* dst4 = (float4*)lds_rows[w];
        const int n4w = nw * NC / 4;           // 336 / 168 / 0
        #pragma unroll
        for (int q = 0; q < 6; ++q) {
            const int fi = lane + 64 * q;
            if (fi < n4w) dst4[fi] = src4[fi];
        }
    }
    // wave-local LDS write->read: explicit wait (no __syncthreads needed)
    asm volatile("s_waitcnt lgkmcnt(0)" ::: "memory");
    __builtin_amdgcn_sched_barrier(0);

    if (valid) {
        const float* myrow = &lds_rows[w][lane * NC];  // stride 21: 2-way alias, free
        float x[NC];
        #pragma unroll
        for (int c = 0; c < NC; ++c) x[c] = myrow[c];  // static indexing only

        // regression targets + SmoothL1 (beta=1), summed over 4 coords
        const float tx = 10.0f * (g.x - a.x) / a.z;
        const float ty = 10.0f * (g.y - a.y) / a.w;
        const float tw = 5.0f * __logf(g.z / a.z);
        const float th = 5.0f * __logf(g.w / a.w);
        float sl1 = 0.f, d, ad;
        d = p.x - tx; ad = fabsf(d); sl1 += (ad < 1.f) ? 0.5f * d * d : ad - 0.5f;
        d = p.y - ty; ad = fabsf(d); sl1 += (ad < 1.f) ? 0.5f * d * d : ad - 0.5f;
        d = p.z - tw; ad = fabsf(d); sl1 += (ad < 1.f) ? 0.5f * d * d : ad - 0.5f;
        d = p.w - th; ad = fabsf(d); sl1 += (ad < 1.f) ? 0.5f * d * d : ad - 0.5f;

        // cross entropy: lse - row[gl]  (gl-indexed read from LDS, NOT registers:
        // runtime-indexing the x[] array would allocate it in scratch — rule #20)
        float m = x[0];
        #pragma unroll
        for (int c = 1; c < NC; ++c) m = fmaxf(m, x[c]);
        float s = 0.f;
        #pragma unroll
        for (int c = 0; c < NC; ++c) s += __expf(x[c] - m);
        const float lse = m + __logf(s);
        const float ce = fmaxf(lse - myrow[gl], 0.f);  // >=0 -> bits order-monotonic

        const bool pos = gl > 0;
        ce_neg[idx] = pos ? 0.f : ce;          // coalesced

        if (pos) {                             // ~5 pos threads: LDS atomics only
            atomicAdd(&st[0], 1.f);
            atomicAdd(&st[1], sl1);
            atomicAdd(&st[2], ce);
        }
    }
    __syncthreads();                           // all ce_neg stores drained (vmcnt0@barrier)

    // ---- arrival: release stats+ce_neg, count 66 blocks per batch ----
    if (tid == 0) {
        partial[blockIdx.x] = make_float4(st[0], st[1], st[2], 0.f);
        __threadfence();                       // release (L2 writeback, device scope)
        s_old = atomicAdd(&bcnt[b], 1);        // 4224 total, 64 lines: no hot spot
    }
    __syncthreads();
    if (s_old != BPB - 1) return;              // only the last block of batch b selects

    // ===================== select phase for batch b (256 threads) =====================
    __threadfence();                           // acquire: invalidate before peer reads

    if (tid < 4) s_stats[tid] = 0.f;
    hist[tid] = 0u;
    __syncthreads();

    // ---- reduce per-block stats (66 entries) ----
    if (tid < BPB) {
        const float4 p0 = partial[b * BPB + tid];
        if (p0.x != 0.f) {
            atomicAdd(&s_stats[0], p0.x);
            atomicAdd(&s_stats[1], p0.y);
            atomicAdd(&s_stats[2], p0.z);
        }
    }

    // ---- 256-bin ballot-histogram over the batch's CE values (L2/L3-hot) ----
    {
        const float4* src = (const float4*)(ce_neg + (size_t)b * NN);
        for (int i = tid; i < NN / 4; i += 256) {
            const float4 v = src[i];
            const uint32_t comp[4] = {__float_as_uint(v.x), __float_as_uint(v.y),
                                      __float_as_uint(v.z), __float_as_uint(v.w)};
            #pragma unroll
            for (int c = 0; c < 4; ++c) {
                const uint32_t dg = comp[c] >> 23;
                unsigned long long act = __ballot(true);
                while (act) {
                    const int leader = __ffsll((long long)act) - 1;
                    const uint32_t dl = __shfl(dg, leader);
                    const unsigned long long same = __ballot(dg == dl) & act;
                    if (lane == leader) atomicAdd(&hist[dl], (uint32_t)__popcll(same));
                    act &= ~same;
                }
            }
        }
    }
    __syncthreads();

    const int pos = (int)(s_stats[0] + 0.5f);
    int k = 3 * pos;                           // NEG_RATIO
    if (k > NN) k = NN;
    if (k < 1) k = 1;                          // pos==0 masked in final

    // ---- coarse pick: wave-parallel suffix scan over 256 bins (descending) ----
    if (w == 0) {
        uint32_t c4[4]; uint32_t cnt = 0;
        #pragma unroll
        for (int t = 0; t < 4; ++t) { c4[t] = hist[255 - (4 * lane + t)]; cnt += c4[t]; }
        uint32_t ic = cnt;
        #pragma unroll
        for (int off = 1; off < 64; off <<= 1) {
            const uint32_t tc = __shfl_up(ic, off);
            if (lane >= off) ic += tc;
        }
        const int exC = (int)(ic - cnt);
        if (exC < k && k <= (int)ic) {         // exactly one lane
            int need = k - exC;
            #pragma unroll
            for (int t = 0; t < 4; ++t) {
                const int c = (int)c4[t];
                if (need <= c) {
                    s_cur = (uint32_t)(255 - (4 * lane + t)) << 23;
                    s_need = need;
                    break;
                }
                need -= c;
            }
        }
    }
    __syncthreads();

    // ---- exact refine of 23 mantissa bits: (sh,nbins)=(15,256),(7,256),(0,128)
    const float* cebase = ce_neg + (size_t)b * NN;
    #pragma unroll
    for (int pp = 0; pp < 3; ++pp) {
        const int sh = (pp == 0) ? 15 : (pp == 1) ? 7 : 0;
        const uint32_t msk = (pp == 0) ? 0xFF800000u : (pp == 1) ? 0xFFFF8000u : 0xFFFFFF80u;
        const int per = (pp == 2) ? 2 : 4;                 // bins per lane
        const uint32_t nbm1 = (pp == 2) ? 127u : 255u;

        h2[tid] = 0u;
        __syncthreads();
        const uint32_t cur = s_cur;
        for (int i = tid; i < NN; i += 256) {
            const uint32_t v = __float_as_uint(cebase[i]);
            if ((v & msk) == cur) atomicAdd(&h2[(v >> sh) & nbm1], 1u);  // ~uniform
        }
        __syncthreads();
        if (w == 0) {
            uint32_t c4[4]; uint32_t cnt = 0;
            #pragma unroll
            for (int t = 0; t < 4; ++t) {
                if (t < per) { c4[t] = h2[nbm1 - (per * lane + t)]; cnt += c4[t]; }
            }
            uint32_t ic = cnt;
            #pragma unroll
            for (int off = 1; off < 64; off <<= 1) {
                const uint32_t tc = __shfl_up(ic, off);
                if (lane >= off) ic += tc;
            }
            const int exC = (int)(ic - cnt);
            const int need_in = s_need;                    // read before write (lockstep)
            if (exC < need_in && need_in <= (int)ic) {     // exactly one lane
                int need = need_in - exC;
                #pragma unroll
                for (int t = 0; t < 4; ++t) {
                    if (t < per) {
                        const int c = (int)c4[t];
                        if (need <= c) {
                            s_cur = cur | ((nbm1 - (uint32_t)(per * lane + t)) << sh);
                            s_need = need;
                            break;
                        }
                        need -= c;
                    }
                }
            }
        }
        __syncthreads();
    }

    // ---- tie-exact top-k sum: sum(v > T) + r*T ----
    const uint32_t T = s_cur;
    const int rf = s_need;
    double loc = 0.0;
    for (int i = tid; i < NN; i += 256) {
        const uint32_t v = __float_as_uint(cebase[i]);
        if (v > T) loc += (double)__uint_as_float(v);
    }
    #pragma unroll
    for (int off = 32; off > 0; off >>= 1) loc += __shfl_down(loc, off);
    if (lane == 0) dpart[w] = loc;
    __syncthreads();

    // ---- publish per-batch results; last select block reduces over B ----
    if (tid == 0) {
        double tot = dpart[0] + dpart[1] + dpart[2] + dpart[3];
        tot += (double)rf * (double)__uint_as_float(T);
        flb[b] = (double)s_stats[1];
        fll[b] = (double)s_stats[2] + tot;
        fpn[b] = pos;
        __threadfence();                       // release
        const int old = atomicAdd(done2, 1);   // 64 total
        s_last = (old == NB - 1) ? 1 : 0;
    }
    __syncthreads();

    if (s_last && w == 0) {
        __threadfence();                       // acquire
        const double lb = flb[lane];           // lane t owns batch t (64 == NB)
        const double ll = fll[lane];
        const int pn = fpn[lane];
        const double nm = (pn > 0) ? 1.0 : 0.0;
        const float pf = fmaxf((float)pn, FP32_EPS_F);
        const double inv = nm / (double)pf;
        double tb = lb * inv;
        double tl = ll * inv;
        double tt = tb + tl;                   // COEFF = (1,1)
        #pragma unroll
        for (int off = 32; off > 0; off >>= 1) {
            tt += __shfl_down(tt, off);
            tb += __shfl_down(tb, off);
            tl += __shfl_down(tl, off);
        }
        if (lane == 0) {
            out[0] = (float)(tt / (double)NB);
            out[1] = (float)(tb / (double)NB);
            out[2] = (float)(tl / (double)NB);
        }
    }
}

// ===================== launcher =====================
extern "C" void kernel_launch(void* const* d_in, const int* in_sizes, int n_in,
                              void* d_out, int out_size, void* d_ws, size_t ws_size,
                              hipStream_t stream)
{
    const float* p_bboxs  = (const float*)d_in[0];
    const float* g_bboxs  = (const float*)d_in[1];
    const float* p_labels = (const float*)d_in[2];
    const int*   g_labels = (const int*)d_in[3];
    const float* ancs     = (const float*)d_in[4];
    float* out = (float*)d_out;

    char* ws = (char*)d_ws;
    float4* partial = (float4*)(ws + OFF_PARTIAL);
    double* flb     = (double*)(ws + OFF_FLB);
    double* fll     = (double*)(ws + OFF_FLL);
    int*    fpn     = (int*)   (ws + OFF_FPN);
    int*    bcnt    = (int*)   (ws + OFF_BCNT);
    int*    done2   = (int*)   (ws + OFF_DONE2);
    float*  ce_neg  = (float*) (ws + OFF_CENEG);

    // zero the arrival counters (512B; graph-capture-safe async memset)
    hipMemsetAsync(ws + OFF_BCNT, 0, 512, stream);

    k_all<<<NBLK, 256, 0, stream>>>(
        p_bboxs, g_bboxs, p_labels, g_labels, ancs,
        ce_neg, partial, flb, fll, fpn, bcnt, done2, out);
}